// Round 16
// baseline (135.086 us; speedup 1.0000x reference)
//
#include <hip/hip_runtime.h>
#include <hip/hip_bf16.h>

#define NN 10000
#define NE 320000
#define CAP 96   // deg ~ Binom(320000,1e-4): mean 32, sd 5.66; P(overflow) < 1e-19

typedef __attribute__((ext_vector_type(8)))  __bf16 bf16x8;
typedef __attribute__((ext_vector_type(16))) float  f32x16;
typedef __attribute__((ext_vector_type(4)))  float  f32x4;

// ======================= bucket scatter =======================
__global__ void scatter_bucket_kernel(const int* __restrict__ eidx,
                                      int* __restrict__ cnt, int2* __restrict__ bucket) {
    for (int e = blockIdx.x * 256 + threadIdx.x; e < NE; e += gridDim.x * 256) {
        int d = eidx[NE + e];
        int s = eidx[e];
        int p = atomicAdd(&cnt[d], 1);
        if (p < CAP) bucket[d * CAP + p] = make_int2(e, s);
    }
}

// ======================= node-centric fused edge + epilogue kernel =======================
// One wave per dst node; 32-edge chunks via MFMA 32x32x16 bf16.
// r16 restructure (post r7-r15 plateau analysis): the sched_barrier walls that
// stop the r5/r6 LICM-spill ALSO serialized gathers+LDS into each window ->
// every config landed 77-88us (VALUBusy ~50%) regardless of occupancy/LDS/ILP
// (r13 proved not-LDS-bound, r15 proved not-LDS-throughput, warm-L2 replays
// proved not-HBM-bound). Fix while keeping walls:
//  (1) ALL global gathers (bucket, ea, 8x xq) issued at chunk start, before
//      the first wall -> latency overlaps early groups instead of puncturing
//      every 4th window.
//  (2) af/ci REGISTER double-buffer: window g = {ds_reads(g+1), MFMA(g),
//      consume(g)} -> next group's reads issue before this group's lgkmcnt
//      wait; LDS latency hides behind MFMA+consume.
// VGPR liveness ~120 (msgr16 + xq32 + 2xaf 8 + 2xci 32 + acc16 + misc):
// (256,2)=128-reg budget (r14 lesson: bound from computed liveness).
__global__ __launch_bounds__(256, 2) void edge_node_kernel(
    const float* __restrict__ x, const float* __restrict__ ea,
    const float* __restrict__ W, const float* __restrict__ be,
    const float* __restrict__ root, const float* __restrict__ bias,
    const int* __restrict__ cnt, const int2* __restrict__ bucket,
    float* __restrict__ out)
{
    __shared__ __attribute__((aligned(16))) __bf16 WT[32][2][32][8];  // 32 KiB
    __shared__ __attribute__((aligned(16))) float  BPF[32][2][16];    // 4 KiB
    __shared__ __attribute__((aligned(16))) float  root_s[32][32];    // 4 KiB
    __shared__ float bias_s[32];
    __shared__ float msum[4][32];

    const int tid = threadIdx.x;

    // stage W via coalesced float4 loads (16/thread vs 64 scalar)
    {
        const f32x4* Wv = (const f32x4*)W;
        #pragma unroll
        for (int t = 0; t < 16; ++t) {
            int u4 = tid + t * 256;            // 4096 float4s = 16384 floats
            f32x4 w4 = Wv[u4];
            int k = u4 >> 8, c0 = (u4 & 255) * 4;
            #pragma unroll
            for (int q = 0; q < 4; ++q) {
                int cg = c0 + q;
                WT[cg >> 5][k >> 3][cg & 31][k & 7] = (__bf16)w4[q];
            }
        }
    }
    #pragma unroll
    for (int k = 0; k < 4; ++k) {
        int idx = tid + k * 256;              // (cb, hi, r) + root staging
        int cb = idx >> 5, rem = idx & 31, hi2 = rem >> 4, r = rem & 15;
        int row = (r & 3) + 8 * (r >> 2) + 4 * hi2;
        BPF[cb][hi2][r] = be[cb * 32 + row];
        root_s[idx >> 5][idx & 31] = root[idx];
    }
    if (tid < 32) bias_s[tid] = bias[tid];
    __syncthreads();

    const int lane = tid & 63;
    const int hi   = lane >> 5;
    const int l31  = lane & 31;
    const int w    = tid >> 6;
    const int n    = blockIdx.x * 4 + w;      // exact: gridDim.x = NN/4

    const int deg = cnt[n];
    const int2* bk = bucket + (size_t)n * CAP;

    float msgr[16];
    #pragma unroll
    for (int r = 0; r < 16; ++r) msgr[r] = 0.0f;

    for (int c0 = 0; c0 < deg; c0 += 32) {
        const int idx  = c0 + l31;
        const bool act = idx < deg;
        const int2 es  = bk[act ? idx : deg - 1];

        // ---- ALL global gathers up front (before any wall) ----
        const f32x4* eap = (const f32x4*)(ea + (size_t)es.x * 16 + hi * 8);
        f32x4 f0 = eap[0];
        f32x4 f1 = eap[1];
        const f32x4* xp = (const f32x4*)(x + (size_t)es.y * 32);
        f32x4 xq[8];
        #pragma unroll
        for (int q = 0; q < 8; ++q) xq[q] = xp[q];

        bf16x8 bfrag;
        bfrag[0]=(__bf16)f0.x; bfrag[1]=(__bf16)f0.y; bfrag[2]=(__bf16)f0.z; bfrag[3]=(__bf16)f0.w;
        bfrag[4]=(__bf16)f1.x; bfrag[5]=(__bf16)f1.y; bfrag[6]=(__bf16)f1.z; bfrag[7]=(__bf16)f1.w;

        if (!act) {
            #pragma unroll
            for (int q = 0; q < 8; ++q) { xq[q].x=0.f; xq[q].y=0.f; xq[q].z=0.f; xq[q].w=0.f; }
        }

        // opaque base: defeats LICM/CSE of the af/ci LDS reads across chunks.
        int base = 0;
        asm volatile("" : "+v"(base));

        // ---- 2-stage register pipeline over the 32 channel-groups ----
        bf16x8 afA = *(const bf16x8*)(&WT[base][hi][l31][0]);
        f32x16 ciA = *(const f32x16*)(&BPF[base][hi][0]);
        #pragma unroll
        for (int g = 0; g < 32; ++g) {
            bf16x8 afB = afA;
            f32x16 ciB = ciA;
            if (g < 31) {
                afB = *(const bf16x8*)(&WT[base + g + 1][hi][l31][0]);
                ciB = *(const f32x16*)(&BPF[base + g + 1][hi][0]);
            }
            f32x16 acc = __builtin_amdgcn_mfma_f32_32x32x16_bf16(afA, bfrag, ciA, 0, 0, 0);
            const float xv = xq[g >> 2][g & 3];
            #pragma unroll
            for (int r = 0; r < 16; ++r)
                msgr[r] += fmaxf(acc[r], 0.0f) * xv;
            __builtin_amdgcn_sched_barrier(0);   // wall: bounds liveness to 2 stages
            afA = afB;
            ciA = ciB;
        }
    }

    // reduce across the 32 slot-lanes within each hi-half
    #pragma unroll
    for (int m = 1; m <= 16; m <<= 1) {
        #pragma unroll
        for (int r = 0; r < 16; ++r)
            msgr[r] += __shfl_xor(msgr[r], m, 64);
    }

    const float rdeg = (deg > 0) ? (1.0f / (float)deg) : 0.0f;
    if (l31 == 0) {
        #pragma unroll
        for (int r = 0; r < 16; ++r) {
            const int o = (r & 3) + 8 * (r >> 2) + 4 * hi;
            msum[w][o] = msgr[r] * rdeg;
        }
    }
    __syncthreads();

    // epilogue: out[n][o] = mean_msg[o] + bias[o] + sum_i x[n][i]*root[i][o]
    const float xv = x[(size_t)n * 32 + l31];
    if (hi == 0) {
        float m = msum[w][l31] + bias_s[l31];
        #pragma unroll
        for (int i = 0; i < 32; ++i)
            m += __shfl(xv, i, 64) * root_s[i][l31];
        out[(size_t)n * 32 + l31] = m;
    }
}

// ======================= launch =======================
extern "C" void kernel_launch(void* const* d_in, const int* in_sizes, int n_in,
                              void* d_out, int out_size, void* d_ws, size_t ws_size,
                              hipStream_t stream) {
    const float* x    = (const float*)d_in[0];
    const int*   eidx = (const int*)d_in[1];     // [2][NE]
    const float* ea   = (const float*)d_in[2];   // [NE][16]
    const float* W    = (const float*)d_in[3];   // [16][1024]
    const float* be   = (const float*)d_in[4];   // [1024]
    const float* root = (const float*)d_in[5];   // [32][32]
    const float* bias = (const float*)d_in[6];   // [32]
    float* out = (float*)d_out;

    // ws: cnt[NN] ints | bucket int2[NN*CAP]
    int*  cnt    = (int*)d_ws;
    int2* bucket = (int2*)((char*)d_ws + ((NN * 4 + 15) & ~15));

    hipMemsetAsync(cnt, 0, NN * sizeof(int), stream);
    scatter_bucket_kernel<<<640, 256, 0, stream>>>(eidx, cnt, bucket);
    edge_node_kernel<<<NN / 4, 256, 0, stream>>>(x, ea, W, be, root, bias,
                                                 cnt, bucket, out);
}